// Round 9
// baseline (555.393 us; speedup 1.0000x reference)
//
#include <hip/hip_runtime.h>
#include <hip/hip_bf16.h>

#define S_N 100000
#define E_N 30000
#define K_N 1000
#define D_K 64
#define F_K 128
#define B_N 16384
#define NNZ_S 1600000
#define NNZ_E 480000
#define NNZ_K 32000
#define NNZ_TOT (NNZ_S + NNZ_E + NNZ_K)

// 128-row buckets for the two-stage scatter
#define NB_S 782  // ceil(100000/128)
#define NB_E 235  // ceil(30000/128)
#define NB_K 8    // ceil(1000/128)
#define NB_TOT (NB_S + NB_E + NB_K)

// stage1 block-local binning: 4096 entries per block
#define CHUNK 4096
#define SB_S 391  // ceil(1600000/4096)
#define SB_E 118  // ceil(480000/4096)
#define SB_K 8    // ceil(32000/4096)
#define SB_TOT (SB_S + SB_E + SB_K)

// fused-kernel block ranges
#define NCONV 8188    // ceil(131000*64/4 / 256)
#define NGATH4 2111   // ceil((2*B_N*64 + K_N*64)/4 / 256)
#define GTOT4 540288  // (2*B_N*64 + K_N*64)/4
#define NIMP4 1024    // B_N*64/4/256
#define FULLB 4094    // ceil(131000*8 / 256)
#define LASTB 1056    // ceil((2*B_N+K_N)*8 / 256)
#define NDENSE 4096   // (B_N/8)*2
#define NKNOW 128     // 1024/8
#define NDISC 4096    // B_N/4

typedef __attribute__((ext_vector_type(8))) short sh8;
typedef __attribute__((ext_vector_type(4))) float f4;
typedef __attribute__((ext_vector_type(8))) unsigned short us8;

__device__ inline float b2f(ushort u) { return __uint_as_float((unsigned)u << 16); }
__device__ inline ushort f2b(float f) {
    unsigned u = __float_as_uint(f);
    return (ushort)((u + 0x7fffu + ((u >> 16) & 1u)) >> 16);
}

// =============================================================== pre kernel
// fuses: convert_bf16 | gather_init(vec4) | bucket_count | impact(vec4)
__global__ void pre_kernel(const float* __restrict__ stu_emb, const float* __restrict__ exer_emb,
                           const float* __restrict__ know_emb,
                           ushort* xb_s, ushort* xb_e, ushort* xb_k,
                           const int* __restrict__ sid, const int* __restrict__ eid,
                           float* bacc_s, float* bacc_e, float* kacc,
                           const int* __restrict__ sr, const int* __restrict__ er,
                           const int* __restrict__ kr, int* bcnt_tot,
                           const float* __restrict__ imp, float* out_imp) {
    int blk = blockIdx.x;
    int t = threadIdx.x;
    if (blk < NCONV) {
        // ---- f32 -> bf16 convert of the three embedding tables
        const int NA = S_N * 64, NB = E_N * 64, NC = K_N * 64;
        int i = (blk * 256 + t) * 4;
        const float* src; ushort* dst;
        if (i < NA) { src = stu_emb; dst = xb_s; }
        else if (i < NA + NB) { i -= NA; src = exer_emb; dst = xb_e; }
        else if (i < NA + NB + NC) { i -= NA + NB; src = know_emb; dst = xb_k; }
        else return;
        float4 v = *(const float4*)&src[i];
        ushort4 o;
        o.x = f2b(v.x); o.y = f2b(v.y); o.z = f2b(v.z); o.w = f2b(v.w);
        *(ushort4*)&dst[i] = o;
    } else if (blk < NCONV + NGATH4) {
        // ---- layer-0 accumulator init from f32 embeddings (float4 lanes)
        int i4 = (blk - NCONV) * 256 + t;
        if (i4 >= GTOT4) return;
        int base = i4 * 4;
        const int BD = B_N * 64;
        if (base < BD) {
            int b = base >> 6, d0 = base & 63;
            *(float4*)&bacc_s[base] = *(const float4*)&stu_emb[(long)sid[b] * 64 + d0];
        } else if (base < 2 * BD) {
            int bb = base - BD; int b = bb >> 6, d0 = bb & 63;
            *(float4*)&bacc_e[bb] = *(const float4*)&exer_emb[(long)eid[b] * 64 + d0];
        } else {
            int bb = base - 2 * BD;
            *(float4*)&kacc[bb] = *(const float4*)&know_emb[bb];
        }
    } else if (blk < NCONV + NGATH4 + SB_TOT) {
        // ---- bucket-level histogram (LDS aggregate -> ~310K global atomics)
        int lb = blk - NCONV - NGATH4;
        const int* rows; int boff, nnz, nb, lblk;
        if (lb < SB_S)            { lblk = lb;              rows = sr; boff = 0;           nnz = NNZ_S; nb = NB_S; }
        else if (lb < SB_S + SB_E){ lblk = lb - SB_S;       rows = er; boff = NB_S;        nnz = NNZ_E; nb = NB_E; }
        else                      { lblk = lb - SB_S - SB_E; rows = kr; boff = NB_S + NB_E; nnz = NNZ_K; nb = NB_K; }
        __shared__ int hist[NB_S];
        for (int i = t; i < nb; i += 256) hist[i] = 0;
        __syncthreads();
        int start = lblk * CHUNK, end = min(start + CHUNK, nnz);
        for (int i = start + t; i < end; i += 256) atomicAdd(&hist[rows[i] >> 7], 1);
        __syncthreads();
        for (int i = t; i < nb; i += 256) {
            int h = hist[i];
            if (h) atomicAdd(&bcnt_tot[boff + i], h);
        }
    } else {
        // ---- impact output gather (float4 lanes)
        int i4 = (blk - NCONV - NGATH4 - SB_TOT) * 256 + t;
        if (i4 >= B_N * 16) return;
        int base = i4 * 4;
        int b = base >> 6, d0 = base & 63;
        *(float4*)&out_imp[base] = *(const float4*)&imp[(long)eid[b] * 64 + d0];
    }
}

// ---- stage 1: block-local LDS binning into bucket windows.
// segment-local bucket bases computed inline (exclusive scan of bcnt_tot).
__global__ void stage1_bin(const int* __restrict__ sr, const int* __restrict__ sc,
                           const float* __restrict__ sv,
                           const int* __restrict__ er, const int* __restrict__ ec,
                           const float* __restrict__ ev,
                           const int* __restrict__ kr, const int* __restrict__ kc,
                           const float* __restrict__ kv,
                           const int* __restrict__ bcnt_tot,
                           int* rsv, int2* stg_s, int2* stg_e, int2* stg_k) {
    int blk = blockIdx.x;
    const int* rows; const int* cols; const float* vals;
    int2* stg; int boff, nnz, nb, lblk;
    if (blk < SB_S) {
        lblk = blk; rows = sr; cols = sc; vals = sv; stg = stg_s;
        boff = 0; nnz = NNZ_S; nb = NB_S;
    } else if (blk < SB_S + SB_E) {
        lblk = blk - SB_S; rows = er; cols = ec; vals = ev; stg = stg_e;
        boff = NB_S; nnz = NNZ_E; nb = NB_E;
    } else {
        lblk = blk - SB_S - SB_E; rows = kr; cols = kc; vals = kv; stg = stg_k;
        boff = NB_S + NB_E; nnz = NNZ_K; nb = NB_K;
    }
    __shared__ int hist[NB_S];
    __shared__ int wbase[NB_S];
    __shared__ int base_l[NB_S];
    __shared__ int sc_s[256];
    int t = threadIdx.x;
    // segment-local exclusive scan of bucket counts (<=782 values)
    int lv[4]; int ls = 0;
    for (int j = 0; j < 4; j++) {
        int idx = t * 4 + j;
        lv[j] = (idx < nb) ? bcnt_tot[boff + idx] : 0;
        ls += lv[j];
    }
    sc_s[t] = ls; __syncthreads();
    for (int off = 1; off < 256; off <<= 1) {
        int x = (t >= off) ? sc_s[t - off] : 0;
        __syncthreads();
        sc_s[t] += x;
        __syncthreads();
    }
    int pre = sc_s[t] - ls;
    for (int j = 0; j < 4; j++) {
        int idx = t * 4 + j;
        if (idx < nb) { base_l[idx] = pre; pre += lv[j]; }
    }
    for (int i = t; i < nb; i += 256) hist[i] = 0;
    __syncthreads();
    int start = lblk * CHUNK, end = min(start + CHUNK, nnz);
    for (int i = start + t; i < end; i += 256) atomicAdd(&hist[rows[i] >> 7], 1);
    __syncthreads();
    for (int i = t; i < nb; i += 256) {
        int h = hist[i];
        int b0 = h ? atomicAdd(&rsv[boff + i], h) : 0;
        wbase[i] = base_l[i] + b0;
        hist[i] = 0;
    }
    __syncthreads();
    for (int i = start + t; i < end; i += 256) {
        int r = rows[i]; int b = r >> 7;
        int p = wbase[b] + atomicAdd(&hist[b], 1);
        stg[p] = make_int2(((r & 127) << 25) | cols[i], __float_as_int(vals[i]));
    }
}

// --------------------------------------------------------- convolution SpMM
// 8-lane group per row, lane owns features 8l..8l+7 (ushort8 = 16B gathers).
// Range form: [j0r, j1r) given directly (used by the fused stage2).
__device__ __forceinline__ void spmm_row_range(
        const int2* __restrict__ pr, int j0r, int j1r,
        const ushort* __restrict__ x, int r, int l, float* a) {
    const us8* __restrict__ X8 = (const us8*)x;
    us8 self = X8[r * 8 + l];
    #pragma unroll
    for (int k = 0; k < 8; k++) a[k] = 0.9f * b2f(self[k]);
    int j = j0r;
    for (; j + 8 <= j1r; j += 8) {
        int2 q[8]; us8 v[8];
        #pragma unroll
        for (int u = 0; u < 8; u++) q[u] = pr[j + u];
        #pragma unroll
        for (int u = 0; u < 8; u++) v[u] = X8[q[u].x * 8 + l];
        #pragma unroll
        for (int u = 0; u < 8; u++) {
            float w = __int_as_float(q[u].y);
            #pragma unroll
            for (int k = 0; k < 8; k++) a[k] = fmaf(w, b2f(v[u][k]), a[k]);
        }
    }
    if (j + 4 <= j1r) {
        int2 q[4]; us8 v[4];
        #pragma unroll
        for (int u = 0; u < 4; u++) q[u] = pr[j + u];
        #pragma unroll
        for (int u = 0; u < 4; u++) v[u] = X8[q[u].x * 8 + l];
        #pragma unroll
        for (int u = 0; u < 4; u++) {
            float w = __int_as_float(q[u].y);
            #pragma unroll
            for (int k = 0; k < 8; k++) a[k] = fmaf(w, b2f(v[u][k]), a[k]);
        }
        j += 4;
    }
    if (j < j1r) {
        // predicated 4-wide tail: clamp indices, zero weights beyond j1r
        int last = j1r - 1;
        int2 q[4]; us8 v[4]; float w[4];
        #pragma unroll
        for (int u = 0; u < 4; u++) q[u] = pr[min(j + u, last)];
        #pragma unroll
        for (int u = 0; u < 4; u++) v[u] = X8[q[u].x * 8 + l];
        #pragma unroll
        for (int u = 0; u < 4; u++) w[u] = (j + u <= last) ? __int_as_float(q[u].y) : 0.f;
        #pragma unroll
        for (int u = 0; u < 4; u++) {
            #pragma unroll
            for (int k = 0; k < 8; k++) a[k] = fmaf(w[u], b2f(v[u][k]), a[k]);
        }
    }
}

__device__ __forceinline__ void spmm_row_compute(
        const int* __restrict__ rp, const int2* __restrict__ pr,
        const ushort* __restrict__ x, int r, int l, float* a) {
    spmm_row_range(pr, rp[r], rp[r + 1], x, r, l, a);
}

__device__ __forceinline__ void spmm_store(ushort* y, int row, int l, const float* a) {
    us8 o;
    #pragma unroll
    for (int k = 0; k < 8; k++) o[k] = f2b(a[k]);
    *(us8*)&y[row * 64 + l * 8] = o;
}

// stage 2 + layer-1 SpMM fused: block per bucket.
// Phase A (placement, identical to R8): inline segment prefix -> j0; per-row
// counts; LDS-scan -> write rp; place stg -> pr. After the placement barrier,
// nx[t] == end offset of row t (cursors ran to completion).
// Phase B: compute the layer-1 SpMM for this bucket's rows from the
// just-written (L2-hot, block-coherent) pr entries.
__global__ void stage2_spmm(const int* __restrict__ bcnt_tot,
                            const int2* __restrict__ stg_s, int2* pr_s, int* rp_s,
                            const ushort* __restrict__ xs, ushort* ys,
                            const int2* __restrict__ stg_e, int2* pr_e, int* rp_e,
                            const ushort* __restrict__ xe, ushort* ye,
                            const int2* __restrict__ stg_k, int2* pr_k, int* rp_k,
                            const ushort* __restrict__ xk, ushort* yk) {
    int gb = blockIdx.x;
    int b = gb;
    const int2* stg; int2* pr; int* rp; const ushort* x; ushort* y;
    int len, segbase, segnnz;
    if (b < NB_S) { stg = stg_s; pr = pr_s; rp = rp_s; x = xs; y = ys; len = S_N; segbase = 0; segnnz = NNZ_S; }
    else if (b < NB_S + NB_E) { b -= NB_S; stg = stg_e; pr = pr_e; rp = rp_e; x = xe; y = ye; len = E_N; segbase = NB_S; segnnz = NNZ_E; }
    else { b -= NB_S + NB_E; stg = stg_k; pr = pr_k; rp = rp_k; x = xk; y = yk; len = K_N; segbase = NB_S + NB_E; segnnz = NNZ_K; }
    int r0 = b << 7;
    int rows = min(128, len - r0);
    __shared__ int cnt[128];
    __shared__ int nx[128];
    __shared__ int red[256];
    int t = threadIdx.x;
    // segment-local prefix: sum bcnt_tot[segbase .. segbase+b)
    int s = 0;
    for (int i = t; i < b; i += 256) s += bcnt_tot[segbase + i];
    red[t] = s;
    if (t < 128) cnt[t] = 0;
    __syncthreads();
    for (int off = 128; off > 0; off >>= 1) {
        if (t < off) red[t] += red[t + off];
        __syncthreads();
    }
    int j0 = red[0];
    int j1 = j0 + bcnt_tot[segbase + b];
    if (b == 0 && t == 0) rp[len] = segnnz;
    for (int j = j0 + t; j < j1; j += 256)
        atomicAdd(&cnt[((unsigned)stg[j].x) >> 25], 1);
    __syncthreads();
    int my = (t < 128) ? cnt[t] : 0;
    for (int off = 1; off < 128; off <<= 1) {
        int y2 = (t < 128 && t >= off) ? cnt[t - off] : 0;
        __syncthreads();
        if (t < 128) cnt[t] += y2;
        __syncthreads();
    }
    if (t < 128) {
        int ex = j0 + cnt[t] - my;   // exclusive prefix within bucket
        nx[t] = ex;
        if (t < rows) rp[r0 + t] = ex;
    }
    __syncthreads();
    for (int j = j0 + t; j < j1; j += 256) {
        int2 e = stg[j];
        int r_rel = ((unsigned)e.x) >> 25;
        int col = e.x & 0x01FFFFFF;
        int p = atomicAdd(&nx[r_rel], 1);
        pr[p] = make_int2(col, e.y);
    }
    __syncthreads();
    // ---- Phase B: layer-1 SpMM for this bucket's rows.
    // nx[t] is now the END of row t; start = (t==0 ? j0 : nx[t-1]).
    int l = t & 7;
    for (int rl = t >> 3; rl < rows; rl += 32) {
        int j0r = (rl == 0) ? j0 : nx[rl - 1];
        int j1r = nx[rl];
        int r = r0 + rl;
        float a[8];
        spmm_row_range(pr, j0r, j1r, x, r, l, a);
        spmm_store(y, r, l, a);
    }
}

__device__ __forceinline__ void spmm_full_body(
        int blk0, int t,
        const int* __restrict__ rp_s, const int2* __restrict__ pr_s,
        const ushort* __restrict__ xs, ushort* ys,
        const int* __restrict__ rp_e, const int2* __restrict__ pr_e,
        const ushort* __restrict__ xe, ushort* ye,
        const int* __restrict__ rp_k, const int2* __restrict__ pr_k,
        const ushort* __restrict__ xk, ushort* yk) {
    int w = (blk0 * 256 + t) >> 3;
    int l = t & 7;
    const int* rp; const int2* pr; const ushort* x; ushort* y; int r;
    if (w < S_N) { rp = rp_s; pr = pr_s; x = xs; y = ys; r = w; }
    else if (w < S_N + E_N) { rp = rp_e; pr = pr_e; x = xe; y = ye; r = w - S_N; }
    else if (w < S_N + E_N + K_N) { rp = rp_k; pr = pr_k; x = xk; y = yk; r = w - S_N - E_N; }
    else return;
    float a[8];
    spmm_row_compute(rp, pr, x, r, l, a);
    spmm_store(y, r, l, a);
}

// vectorized gather-accumulate (float4 per lane)
__device__ __forceinline__ void gather_accb_body4(
        int i4, const int* __restrict__ sid, const int* __restrict__ eid,
        const ushort* __restrict__ src_s, const ushort* __restrict__ src_e,
        const ushort* __restrict__ src_k,
        float* bacc_s, float* bacc_e, float* kacc) {
    if (i4 >= GTOT4) return;
    int base = i4 * 4;
    const int BD = B_N * 64;
    const ushort* src; float* acc; long soff; int aoff;
    if (base < BD) {
        int b = base >> 6, d0 = base & 63;
        src = src_s; acc = bacc_s; soff = (long)sid[b] * 64 + d0; aoff = base;
    } else if (base < 2 * BD) {
        int bb = base - BD; int b = bb >> 6, d0 = bb & 63;
        src = src_e; acc = bacc_e; soff = (long)eid[b] * 64 + d0; aoff = bb;
    } else {
        int bb = base - 2 * BD;
        src = src_k; acc = kacc; soff = bb; aoff = bb;
    }
    ushort4 v = *(const ushort4*)&src[soff];
    float4 a = *(const float4*)&acc[aoff];
    a.x += b2f(v.x); a.y += b2f(v.y); a.z += b2f(v.z); a.w += b2f(v.w);
    *(float4*)&acc[aoff] = a;
}

// layer-2: full-table spmm (bufA->bufB) fused with gather_accb(bufA)
__global__ void spmm_l2_fused(const int* __restrict__ rp_s, const int2* __restrict__ pr_s,
                              const ushort* __restrict__ xs, ushort* ys,
                              const int* __restrict__ rp_e, const int2* __restrict__ pr_e,
                              const ushort* __restrict__ xe, ushort* ye,
                              const int* __restrict__ rp_k, const int2* __restrict__ pr_k,
                              const ushort* __restrict__ xk, ushort* yk,
                              const int* __restrict__ sid, const int* __restrict__ eid,
                              float* bacc_s, float* bacc_e, float* kacc) {
    int blk = blockIdx.x;
    if (blk < FULLB) {
        spmm_full_body(blk, threadIdx.x, rp_s, pr_s, xs, ys,
                       rp_e, pr_e, xe, ye, rp_k, pr_k, xk, yk);
    } else {
        int i4 = (blk - FULLB) * 256 + threadIdx.x;
        gather_accb_body4(i4, sid, eid, xs, xe, xk, bacc_s, bacc_e, kacc);
    }
}

// layer-3: batch-rows spmm (bufB->c3) + full K, fused with gather_accb(bufB)
__global__ void spmm_l3_fused(const int* __restrict__ sid, const int* __restrict__ eid,
                              const int* __restrict__ rp_s, const int2* __restrict__ pr_s,
                              const ushort* __restrict__ xs, ushort* c3s,
                              const int* __restrict__ rp_e, const int2* __restrict__ pr_e,
                              const ushort* __restrict__ xe, ushort* c3e,
                              const int* __restrict__ rp_k, const int2* __restrict__ pr_k,
                              const ushort* __restrict__ xk, ushort* yk,
                              float* bacc_s, float* bacc_e, float* kacc) {
    int blk = blockIdx.x;
    int t = threadIdx.x;
    if (blk < LASTB) {
        int w = (blk * 256 + t) >> 3;
        int l = t & 7;
        const int* rp; const int2* pr; const ushort* x; ushort* y; int r; int orow;
        if (w < B_N) { rp = rp_s; pr = pr_s; x = xs; y = c3s; r = sid[w]; orow = w; }
        else if (w < 2 * B_N) {
            int b = w - B_N;
            rp = rp_e; pr = pr_e; x = xe; y = c3e; r = eid[b]; orow = b;
        } else if (w < 2 * B_N + K_N) {
            r = w - 2 * B_N;
            rp = rp_k; pr = pr_k; x = xk; y = yk; orow = r;
        } else return;
        float a[8];
        spmm_row_compute(rp, pr, x, r, l, a);
        spmm_store(y, orow, l, a);
    } else {
        int i4 = (blk - LASTB) * 256 + t;
        gather_accb_body4(i4, sid, eid, xs, xe, xk, bacc_s, bacc_e, kacc);
    }
}

// =============================================================== post kernel
// fuses dense_mm | know_mm | disc. Dense blocks cover 8 rows each with a
// register-shared W value across 4 row-accumulators (W L2 traffic /4).
__global__ void post_kernel(const float* __restrict__ bacc_s, const ushort* __restrict__ c3_s,
                            const float* __restrict__ bacc_e, const ushort* __restrict__ c3_e,
                            const float* __restrict__ W_stu, const float* __restrict__ b_stu,
                            const float* __restrict__ W_exer, const float* __restrict__ b_exer,
                            __hip_bfloat16* st_b, __hip_bfloat16* df_b,
                            const float* __restrict__ kacc, const ushort* __restrict__ cur3_k,
                            const float* __restrict__ W_know, const float* __restrict__ b_know,
                            float* out_kn_f32, __hip_bfloat16* kn_b,
                            const float* __restrict__ W_disc, const float* __restrict__ b_disc,
                            float* out_disc) {
    int blk = blockIdx.x;
    int t = threadIdx.x;
    if (blk < NDENSE) {
        int which = blk >> 11;                 // 2048 blocks each
        int local = blk & 2047;
        const float* bacc = which ? bacc_e : bacc_s;
        const ushort* c3 = which ? c3_e : c3_s;
        const float* W = which ? W_exer : W_stu;
        const float* bias = which ? b_exer : b_stu;
        __hip_bfloat16* out = which ? df_b : st_b;
        int r0 = local * 8;
        __shared__ float X[8][64];
        // stage 8 rows (512 elems, 2 per thread)
        for (int i = t; i < 512; i += 256) {
            int lr = i >> 6, d = i & 63; int b = r0 + lr;
            X[lr][d] = 0.25f * (bacc[(long)b * 64 + d] + b2f(c3[(long)b * 64 + d]));
        }
        __syncthreads();
        int lr = t >> 7, f = t & 127;   // thread covers rows lr, lr+2, lr+4, lr+6
        float acc[4];
        #pragma unroll
        for (int rr = 0; rr < 4; rr++) acc[rr] = bias[f];
        for (int d = 0; d < 64; d++) {
            float wv = W[d * 128 + f];
            #pragma unroll
            for (int rr = 0; rr < 4; rr++) acc[rr] += X[rr * 2 + lr][d] * wv;
        }
        #pragma unroll
        for (int rr = 0; rr < 4; rr++) {
            float a = acc[rr];
            a = a > 0.f ? a : 0.1f * a;
            out[(long)(r0 + rr * 2 + lr) * 128 + f] = __float2bfloat16(a);
        }
    } else if (blk < NDENSE + NKNOW) {
        int r0 = (blk - NDENSE) * 8;
        __shared__ float X[8][64];
        for (int i = t; i < 512; i += 256) {
            int lr = i >> 6, d = i & 63; int r = r0 + lr;
            X[lr][d] = (r < K_N) ? 0.25f * (kacc[r * 64 + d] + b2f(cur3_k[r * 64 + d])) : 0.f;
        }
        __syncthreads();
        int lr = t >> 7, f = t & 127;
        float acc[4];
        #pragma unroll
        for (int rr = 0; rr < 4; rr++) acc[rr] = b_know[f];
        for (int d = 0; d < 64; d++) {
            float wv = W_know[d * 128 + f];
            #pragma unroll
            for (int rr = 0; rr < 4; rr++) acc[rr] += X[rr * 2 + lr][d] * wv;
        }
        #pragma unroll
        for (int rr = 0; rr < 4; rr++) {
            int r = r0 + rr * 2 + lr;
            float a = acc[rr];
            a = a > 0.f ? a : 0.1f * a;
            if (r < K_N) {
                out_kn_f32[(long)r * 128 + f] = a;
                kn_b[(long)r * 128 + f] = __float2bfloat16(a);
            } else {
                kn_b[(long)r * 128 + f] = __float2bfloat16(0.f);
            }
        }
    } else {
        int w = ((blk - NDENSE - NKNOW) * 256 + t) >> 6;
        int d = t & 63;
        if (w >= B_N) return;
        float x = 0.25f * (bacc_e[(long)w * 64 + d] + b2f(c3_e[(long)w * 64 + d])) * W_disc[d];
        for (int off = 32; off > 0; off >>= 1) x += __shfl_down(x, off, 64);
        if (d == 0) {
            float z = x + b_disc[0];
            out_disc[w] = 1.f / (1.f + expf(-z));
        }
    }
}

// --------------------------------------------- big GEMM: [B,128] @ [128,1024p]^T
// block = 64 rows x 256 cols (wave: 32x128 = 2x8 mfma tiles)
__global__ void big_mm(const __hip_bfloat16* __restrict__ st, const __hip_bfloat16* __restrict__ df,
                       const __hip_bfloat16* __restrict__ kn,
                       float* __restrict__ out0, float* __restrict__ out1) {
    const ushort* X = (const ushort*)(blockIdx.z ? df : st);
    const ushort* Kn = (const ushort*)kn;
    float* out = blockIdx.z ? out1 : out0;
    int wv = threadIdx.x >> 6;
    int lane = threadIdx.x & 63;
    int m_blk = blockIdx.y * 64 + (wv >> 1) * 32;
    int n_blk = blockIdx.x * 256 + (wv & 1) * 128;
    int q = lane >> 4, l16 = lane & 15;
    f4 acc0[8], acc1[8];
    #pragma unroll
    for (int nt = 0; nt < 8; nt++) { acc0[nt] = {0.f, 0.f, 0.f, 0.f}; acc1[nt] = acc0[nt]; }
    for (int s = 0; s < 4; s++) {
        int kofs = s * 32 + q * 8;
        sh8 a0 = *(const sh8*)&X[(long)(m_blk + l16) * 128 + kofs];
        sh8 a1 = *(const sh8*)&X[(long)(m_blk + 16 + l16) * 128 + kofs];
        #pragma unroll
        for (int nt = 0; nt < 8; nt++) {
            sh8 bb = *(const sh8*)&Kn[(long)(n_blk + nt * 16 + l16) * 128 + kofs];
            acc0[nt] = __builtin_amdgcn_mfma_f32_16x16x32_bf16(a0, bb, acc0[nt], 0, 0, 0);
            acc1[nt] = __builtin_amdgcn_mfma_f32_16x16x32_bf16(a1, bb, acc1[nt], 0, 0, 0);
        }
    }
    // C/D layout: col = lane&15, row = (lane>>4)*4 + reg
    #pragma unroll
    for (int nt = 0; nt < 8; nt++) {
        int col = n_blk + nt * 16 + l16;
        if (col >= K_N) continue;
        #pragma unroll
        for (int r = 0; r < 4; r++) {
            out[(long)(m_blk + q * 4 + r) * K_N + col] = acc0[nt][r];
            out[(long)(m_blk + 16 + q * 4 + r) * K_N + col] = acc1[nt][r];
        }
    }
}

// ---------------------------------------------------------------------------
extern "C" void kernel_launch(void* const* d_in, const int* in_sizes, int n_in,
                              void* d_out, int out_size, void* d_ws, size_t ws_size,
                              hipStream_t stream) {
    const int* sid = (const int*)d_in[0];
    const int* eid = (const int*)d_in[1];
    // d_in[2] q_mask unused
    const float* stu_emb = (const float*)d_in[3];
    const float* exer_emb = (const float*)d_in[4];
    const float* know_emb = (const float*)d_in[5];
    const float* impact_emb = (const float*)d_in[6];
    const int* s_rows = (const int*)d_in[7];
    const int* s_cols = (const int*)d_in[8];
    const float* s_vals = (const float*)d_in[9];
    const int* e_rows = (const int*)d_in[10];
    const int* e_cols = (const int*)d_in[11];
    const float* e_vals = (const float*)d_in[12];
    const int* k_rows = (const int*)d_in[13];
    const int* k_cols = (const int*)d_in[14];
    const float* k_vals = (const float*)d_in[15];
    const float* W_stu = (const float*)d_in[16];
    const float* b_stu = (const float*)d_in[17];
    const float* W_exer = (const float*)d_in[18];
    const float* b_exer = (const float*)d_in[19];
    const float* W_know = (const float*)d_in[20];
    const float* b_know = (const float*)d_in[21];
    const float* W_disc = (const float*)d_in[22];
    const float* b_disc = (const float*)d_in[23];

    float* out = (float*)d_out;
    float* out_st = out;                       // [B,1000]
    float* out_df = out + 16384000;            // [B,1000]
    float* out_disc = out + 32768000;          // [B,1]
    float* out_kn = out + 32784384;            // [1000,128]
    float* out_imp = out + 32912384;           // [B,64]

    char* p = (char*)d_ws;
    auto alloc = [&](size_t bytes) -> char* {
        char* r = p;
        p += (bytes + 255) & ~(size_t)255;
        return r;
    };
    ushort* xb_s = (ushort*)alloc((size_t)S_N * 64 * 2);   // bf16 embeddings
    ushort* xb_e = (ushort*)alloc((size_t)E_N * 64 * 2);
    ushort* xb_k = (ushort*)alloc((size_t)K_N * 64 * 2);
    ushort* bufA_s = (ushort*)alloc((size_t)S_N * 64 * 2);
    ushort* bufB_s = (ushort*)alloc((size_t)S_N * 64 * 2);
    ushort* bufA_e = (ushort*)alloc((size_t)E_N * 64 * 2);
    ushort* bufB_e = (ushort*)alloc((size_t)E_N * 64 * 2);
    ushort* bufA_k = (ushort*)alloc((size_t)K_N * 64 * 2);
    ushort* bufB_k = (ushort*)alloc((size_t)K_N * 64 * 2);
    ushort* c3s = (ushort*)alloc((size_t)B_N * 64 * 2);    // layer-3 per-batch rows
    ushort* c3e = (ushort*)alloc((size_t)B_N * 64 * 2);
    float* bacc_s = (float*)alloc((size_t)B_N * 64 * 4);
    float* bacc_e = (float*)alloc((size_t)B_N * 64 * 4);
    float* kacc = (float*)alloc((size_t)K_N * 64 * 4);
    __hip_bfloat16* st_b = (__hip_bfloat16*)alloc((size_t)B_N * 128 * 2);
    __hip_bfloat16* df_b = (__hip_bfloat16*)alloc((size_t)B_N * 128 * 2);
    __hip_bfloat16* kn_b = (__hip_bfloat16*)alloc((size_t)1024 * 128 * 2);
    // bucket totals + reservation cursors (zeroed together)
    int* bcnt_tot = (int*)alloc((size_t)2 * NB_TOT * 4);
    int* rsv = bcnt_tot + NB_TOT;
    int* rp_s = (int*)alloc((size_t)(S_N + 1) * 4);
    int* rp_e = (int*)alloc((size_t)(E_N + 1) * 4);
    int* rp_k = (int*)alloc((size_t)(K_N + 1) * 4);
    int2* stg_s = (int2*)alloc((size_t)NNZ_S * 8);
    int2* stg_e = (int2*)alloc((size_t)NNZ_E * 8);
    int2* stg_k = (int2*)alloc((size_t)NNZ_K * 8);
    int2* pr_s = (int2*)alloc((size_t)NNZ_S * 8);
    int2* pr_e = (int2*)alloc((size_t)NNZ_E * 8);
    int2* pr_k = (int2*)alloc((size_t)NNZ_K * 8);

    // 1) zero counters
    hipMemsetAsync(bcnt_tot, 0, (size_t)2 * NB_TOT * 4, stream);
    // 2) fused: convert + gather_init + bucket_count + impact
    pre_kernel<<<NCONV + NGATH4 + SB_TOT + NIMP4, 256, 0, stream>>>(
        stu_emb, exer_emb, know_emb, xb_s, xb_e, xb_k,
        sid, eid, bacc_s, bacc_e, kacc,
        s_rows, e_rows, k_rows, bcnt_tot, impact_emb, out_imp);
    // 3) stage1 (inline segment scan)
    stage1_bin<<<SB_TOT, 256, 0, stream>>>(
        s_rows, s_cols, s_vals, e_rows, e_cols, e_vals, k_rows, k_cols, k_vals,
        bcnt_tot, rsv, stg_s, stg_e, stg_k);
    // 4) stage2 placement + layer-1 SpMM fused (per-bucket, L2-hot pr)
    stage2_spmm<<<NB_TOT, 256, 0, stream>>>(bcnt_tot,
                                            stg_s, pr_s, rp_s, xb_s, bufA_s,
                                            stg_e, pr_e, rp_e, xb_e, bufA_e,
                                            stg_k, pr_k, rp_k, xb_k, bufA_k);
    // 5) layer-2 spmm + gather_accb(bufA)
    spmm_l2_fused<<<FULLB + NGATH4, 256, 0, stream>>>(
        rp_s, pr_s, bufA_s, bufB_s,
        rp_e, pr_e, bufA_e, bufB_e,
        rp_k, pr_k, bufA_k, bufB_k,
        sid, eid, bacc_s, bacc_e, kacc);
    // 6) layer-3 batched spmm + gather_accb(bufB)
    spmm_l3_fused<<<LASTB + NGATH4, 256, 0, stream>>>(
        sid, eid,
        rp_s, pr_s, bufB_s, c3s,
        rp_e, pr_e, bufB_e, c3e,
        rp_k, pr_k, bufB_k, bufA_k,
        bacc_s, bacc_e, kacc);
    // 7) fused dense stage (8-row dense blocks)
    post_kernel<<<NDENSE + NKNOW + NDISC, 256, 0, stream>>>(
        bacc_s, c3s, bacc_e, c3e, W_stu, b_stu, W_exer, b_exer, st_b, df_b,
        kacc, bufA_k, W_know, b_know, out_kn, kn_b,
        W_disc, b_disc, out_disc);
    // 8) big GEMMs (64x256 blocks)
    big_mm<<<dim3(4, B_N / 64, 2), 256, 0, stream>>>(st_b, df_b, kn_b, out_st, out_df);
}

// Round 10
// 543.382 us; speedup vs baseline: 1.0221x; 1.0221x over previous
//
#include <hip/hip_runtime.h>
#include <hip/hip_bf16.h>

#define S_N 100000
#define E_N 30000
#define K_N 1000
#define D_K 64
#define F_K 128
#define B_N 16384
#define NNZ_S 1600000
#define NNZ_E 480000
#define NNZ_K 32000
#define NNZ_TOT (NNZ_S + NNZ_E + NNZ_K)

// 128-row buckets for the two-stage scatter
#define NB_S 782  // ceil(100000/128)
#define NB_E 235  // ceil(30000/128)
#define NB_K 8    // ceil(1000/128)
#define NB_TOT (NB_S + NB_E + NB_K)

// stage1 block-local binning: 4096 entries per block
#define CHUNK 4096
#define SB_S 391  // ceil(1600000/4096)
#define SB_E 118  // ceil(480000/4096)
#define SB_K 8    // ceil(32000/4096)
#define SB_TOT (SB_S + SB_E + SB_K)

// fused-kernel block ranges
#define NCONV 8188    // ceil(131000*64/4 / 256)
#define NGATH4 2111   // ceil((2*B_N*64 + K_N*64)/4 / 256)
#define GTOT4 540288  // (2*B_N*64 + K_N*64)/4
#define NIMP4 1024    // B_N*64/4/256
#define FULLB 4094    // ceil(131000*8 / 256)
#define LASTB 1056    // ceil((2*B_N+K_N)*8 / 256)
#define NDENSE 4096   // (B_N/8)*2
#define NKNOW 128     // 1024/8
#define NDISC 4096    // B_N/4

typedef __attribute__((ext_vector_type(8))) short sh8;
typedef __attribute__((ext_vector_type(4))) float f4;
typedef __attribute__((ext_vector_type(8))) unsigned short us8;

__device__ inline float b2f(ushort u) { return __uint_as_float((unsigned)u << 16); }
__device__ inline ushort f2b(float f) {
    unsigned u = __float_as_uint(f);
    return (ushort)((u + 0x7fffu + ((u >> 16) & 1u)) >> 16);
}

// =============================================================== pre kernel
// fuses: convert_bf16 | gather_init(vec4) | bucket_count | impact(vec4)
__global__ void pre_kernel(const float* __restrict__ stu_emb, const float* __restrict__ exer_emb,
                           const float* __restrict__ know_emb,
                           ushort* xb_s, ushort* xb_e, ushort* xb_k,
                           const int* __restrict__ sid, const int* __restrict__ eid,
                           float* bacc_s, float* bacc_e, float* kacc,
                           const int* __restrict__ sr, const int* __restrict__ er,
                           const int* __restrict__ kr, int* bcnt_tot,
                           const float* __restrict__ imp, float* out_imp) {
    int blk = blockIdx.x;
    int t = threadIdx.x;
    if (blk < NCONV) {
        // ---- f32 -> bf16 convert of the three embedding tables
        const int NA = S_N * 64, NB = E_N * 64, NC = K_N * 64;
        int i = (blk * 256 + t) * 4;
        const float* src; ushort* dst;
        if (i < NA) { src = stu_emb; dst = xb_s; }
        else if (i < NA + NB) { i -= NA; src = exer_emb; dst = xb_e; }
        else if (i < NA + NB + NC) { i -= NA + NB; src = know_emb; dst = xb_k; }
        else return;
        float4 v = *(const float4*)&src[i];
        ushort4 o;
        o.x = f2b(v.x); o.y = f2b(v.y); o.z = f2b(v.z); o.w = f2b(v.w);
        *(ushort4*)&dst[i] = o;
    } else if (blk < NCONV + NGATH4) {
        // ---- layer-0 accumulator init from f32 embeddings (float4 lanes)
        int i4 = (blk - NCONV) * 256 + t;
        if (i4 >= GTOT4) return;
        int base = i4 * 4;
        const int BD = B_N * 64;
        if (base < BD) {
            int b = base >> 6, d0 = base & 63;
            *(float4*)&bacc_s[base] = *(const float4*)&stu_emb[(long)sid[b] * 64 + d0];
        } else if (base < 2 * BD) {
            int bb = base - BD; int b = bb >> 6, d0 = bb & 63;
            *(float4*)&bacc_e[bb] = *(const float4*)&exer_emb[(long)eid[b] * 64 + d0];
        } else {
            int bb = base - 2 * BD;
            *(float4*)&kacc[bb] = *(const float4*)&know_emb[bb];
        }
    } else if (blk < NCONV + NGATH4 + SB_TOT) {
        // ---- bucket-level histogram (LDS aggregate -> ~310K global atomics)
        int lb = blk - NCONV - NGATH4;
        const int* rows; int boff, nnz, nb, lblk;
        if (lb < SB_S)            { lblk = lb;              rows = sr; boff = 0;           nnz = NNZ_S; nb = NB_S; }
        else if (lb < SB_S + SB_E){ lblk = lb - SB_S;       rows = er; boff = NB_S;        nnz = NNZ_E; nb = NB_E; }
        else                      { lblk = lb - SB_S - SB_E; rows = kr; boff = NB_S + NB_E; nnz = NNZ_K; nb = NB_K; }
        __shared__ int hist[NB_S];
        for (int i = t; i < nb; i += 256) hist[i] = 0;
        __syncthreads();
        int start = lblk * CHUNK, end = min(start + CHUNK, nnz);
        for (int i = start + t; i < end; i += 256) atomicAdd(&hist[rows[i] >> 7], 1);
        __syncthreads();
        for (int i = t; i < nb; i += 256) {
            int h = hist[i];
            if (h) atomicAdd(&bcnt_tot[boff + i], h);
        }
    } else {
        // ---- impact output gather (float4 lanes)
        int i4 = (blk - NCONV - NGATH4 - SB_TOT) * 256 + t;
        if (i4 >= B_N * 16) return;
        int base = i4 * 4;
        int b = base >> 6, d0 = base & 63;
        *(float4*)&out_imp[base] = *(const float4*)&imp[(long)eid[b] * 64 + d0];
    }
}

// ---- stage 1: block-local LDS binning into bucket windows.
// segment-local bucket bases computed inline (exclusive scan of bcnt_tot).
__global__ void stage1_bin(const int* __restrict__ sr, const int* __restrict__ sc,
                           const float* __restrict__ sv,
                           const int* __restrict__ er, const int* __restrict__ ec,
                           const float* __restrict__ ev,
                           const int* __restrict__ kr, const int* __restrict__ kc,
                           const float* __restrict__ kv,
                           const int* __restrict__ bcnt_tot,
                           int* rsv, int2* stg_s, int2* stg_e, int2* stg_k) {
    int blk = blockIdx.x;
    const int* rows; const int* cols; const float* vals;
    int2* stg; int boff, nnz, nb, lblk;
    if (blk < SB_S) {
        lblk = blk; rows = sr; cols = sc; vals = sv; stg = stg_s;
        boff = 0; nnz = NNZ_S; nb = NB_S;
    } else if (blk < SB_S + SB_E) {
        lblk = blk - SB_S; rows = er; cols = ec; vals = ev; stg = stg_e;
        boff = NB_S; nnz = NNZ_E; nb = NB_E;
    } else {
        lblk = blk - SB_S - SB_E; rows = kr; cols = kc; vals = kv; stg = stg_k;
        boff = NB_S + NB_E; nnz = NNZ_K; nb = NB_K;
    }
    __shared__ int hist[NB_S];
    __shared__ int wbase[NB_S];
    __shared__ int base_l[NB_S];
    __shared__ int sc_s[256];
    int t = threadIdx.x;
    // segment-local exclusive scan of bucket counts (<=782 values)
    int lv[4]; int ls = 0;
    for (int j = 0; j < 4; j++) {
        int idx = t * 4 + j;
        lv[j] = (idx < nb) ? bcnt_tot[boff + idx] : 0;
        ls += lv[j];
    }
    sc_s[t] = ls; __syncthreads();
    for (int off = 1; off < 256; off <<= 1) {
        int x = (t >= off) ? sc_s[t - off] : 0;
        __syncthreads();
        sc_s[t] += x;
        __syncthreads();
    }
    int pre = sc_s[t] - ls;
    for (int j = 0; j < 4; j++) {
        int idx = t * 4 + j;
        if (idx < nb) { base_l[idx] = pre; pre += lv[j]; }
    }
    for (int i = t; i < nb; i += 256) hist[i] = 0;
    __syncthreads();
    int start = lblk * CHUNK, end = min(start + CHUNK, nnz);
    for (int i = start + t; i < end; i += 256) atomicAdd(&hist[rows[i] >> 7], 1);
    __syncthreads();
    for (int i = t; i < nb; i += 256) {
        int h = hist[i];
        int b0 = h ? atomicAdd(&rsv[boff + i], h) : 0;
        wbase[i] = base_l[i] + b0;
        hist[i] = 0;
    }
    __syncthreads();
    for (int i = start + t; i < end; i += 256) {
        int r = rows[i]; int b = r >> 7;
        int p = wbase[b] + atomicAdd(&hist[b], 1);
        stg[p] = make_int2(((r & 127) << 25) | cols[i], __float_as_int(vals[i]));
    }
}

// stage 2: block per bucket. Inline prefix (sum of prior buckets in segment),
// per-row counts from staged entries, LDS-scan -> write rp, then place.
__global__ void stage2_place(const int* __restrict__ bcnt_tot,
                             const int2* __restrict__ stg_s, int2* pr_s, int* rp_s,
                             const int2* __restrict__ stg_e, int2* pr_e, int* rp_e,
                             const int2* __restrict__ stg_k, int2* pr_k, int* rp_k) {
    int gb = blockIdx.x;
    int b = gb;
    const int2* stg; int2* pr; int* rp; int len, segbase, segnnz;
    if (b < NB_S) { stg = stg_s; pr = pr_s; rp = rp_s; len = S_N; segbase = 0; segnnz = NNZ_S; }
    else if (b < NB_S + NB_E) { b -= NB_S; stg = stg_e; pr = pr_e; rp = rp_e; len = E_N; segbase = NB_S; segnnz = NNZ_E; }
    else { b -= NB_S + NB_E; stg = stg_k; pr = pr_k; rp = rp_k; len = K_N; segbase = NB_S + NB_E; segnnz = NNZ_K; }
    int r0 = b << 7;
    int rows = min(128, len - r0);
    __shared__ int cnt[128];
    __shared__ int nx[128];
    __shared__ int red[256];
    int t = threadIdx.x;
    // segment-local prefix: sum bcnt_tot[segbase .. segbase+b)
    int s = 0;
    for (int i = t; i < b; i += 256) s += bcnt_tot[segbase + i];
    red[t] = s;
    if (t < 128) cnt[t] = 0;
    __syncthreads();
    for (int off = 128; off > 0; off >>= 1) {
        if (t < off) red[t] += red[t + off];
        __syncthreads();
    }
    int j0 = red[0];
    int j1 = j0 + bcnt_tot[segbase + b];
    if (b == 0 && t == 0) rp[len] = segnnz;
    for (int j = j0 + t; j < j1; j += 256)
        atomicAdd(&cnt[((unsigned)stg[j].x) >> 25], 1);
    __syncthreads();
    int my = (t < 128) ? cnt[t] : 0;
    for (int off = 1; off < 128; off <<= 1) {
        int y = (t < 128 && t >= off) ? cnt[t - off] : 0;
        __syncthreads();
        if (t < 128) cnt[t] += y;
        __syncthreads();
    }
    if (t < 128) {
        int ex = j0 + cnt[t] - my;   // exclusive prefix within bucket
        nx[t] = ex;
        if (t < rows) rp[r0 + t] = ex;
    }
    __syncthreads();
    for (int j = j0 + t; j < j1; j += 256) {
        int2 e = stg[j];
        int r_rel = ((unsigned)e.x) >> 25;
        int col = e.x & 0x01FFFFFF;
        int p = atomicAdd(&nx[r_rel], 1);
        pr[p] = make_int2(col, e.y);
    }
}

// --------------------------------------------------------- convolution SpMM
// 8-lane group per row, lane owns features 8l..8l+7 (ushort8 = 16B gathers).
__device__ __forceinline__ void spmm_row_compute(
        const int* __restrict__ rp, const int2* __restrict__ pr,
        const ushort* __restrict__ x, int r, int l, float* a) {
    const us8* __restrict__ X8 = (const us8*)x;
    int j0 = rp[r], j1 = rp[r + 1];
    us8 self = X8[r * 8 + l];
    #pragma unroll
    for (int k = 0; k < 8; k++) a[k] = 0.9f * b2f(self[k]);
    int j = j0;
    for (; j + 8 <= j1; j += 8) {
        int2 q[8]; us8 v[8];
        #pragma unroll
        for (int u = 0; u < 8; u++) q[u] = pr[j + u];
        #pragma unroll
        for (int u = 0; u < 8; u++) v[u] = X8[q[u].x * 8 + l];
        #pragma unroll
        for (int u = 0; u < 8; u++) {
            float w = __int_as_float(q[u].y);
            #pragma unroll
            for (int k = 0; k < 8; k++) a[k] = fmaf(w, b2f(v[u][k]), a[k]);
        }
    }
    if (j + 4 <= j1) {
        int2 q[4]; us8 v[4];
        #pragma unroll
        for (int u = 0; u < 4; u++) q[u] = pr[j + u];
        #pragma unroll
        for (int u = 0; u < 4; u++) v[u] = X8[q[u].x * 8 + l];
        #pragma unroll
        for (int u = 0; u < 4; u++) {
            float w = __int_as_float(q[u].y);
            #pragma unroll
            for (int k = 0; k < 8; k++) a[k] = fmaf(w, b2f(v[u][k]), a[k]);
        }
        j += 4;
    }
    if (j < j1) {
        // predicated 4-wide tail: clamp indices, zero weights beyond j1
        int last = j1 - 1;
        int2 q[4]; us8 v[4]; float w[4];
        #pragma unroll
        for (int u = 0; u < 4; u++) q[u] = pr[min(j + u, last)];
        #pragma unroll
        for (int u = 0; u < 4; u++) v[u] = X8[q[u].x * 8 + l];
        #pragma unroll
        for (int u = 0; u < 4; u++) w[u] = (j + u <= last) ? __int_as_float(q[u].y) : 0.f;
        #pragma unroll
        for (int u = 0; u < 4; u++) {
            #pragma unroll
            for (int k = 0; k < 8; k++) a[k] = fmaf(w[u], b2f(v[u][k]), a[k]);
        }
    }
}

__device__ __forceinline__ void spmm_store(ushort* y, int row, int l, const float* a) {
    us8 o;
    #pragma unroll
    for (int k = 0; k < 8; k++) o[k] = f2b(a[k]);
    *(us8*)&y[row * 64 + l * 8] = o;
}

__device__ __forceinline__ void spmm_full_body(
        int blk0, int t,
        const int* __restrict__ rp_s, const int2* __restrict__ pr_s,
        const ushort* __restrict__ xs, ushort* ys,
        const int* __restrict__ rp_e, const int2* __restrict__ pr_e,
        const ushort* __restrict__ xe, ushort* ye,
        const int* __restrict__ rp_k, const int2* __restrict__ pr_k,
        const ushort* __restrict__ xk, ushort* yk) {
    int w = (blk0 * 256 + t) >> 3;
    int l = t & 7;
    const int* rp; const int2* pr; const ushort* x; ushort* y; int r;
    if (w < S_N) { rp = rp_s; pr = pr_s; x = xs; y = ys; r = w; }
    else if (w < S_N + E_N) { rp = rp_e; pr = pr_e; x = xe; y = ye; r = w - S_N; }
    else if (w < S_N + E_N + K_N) { rp = rp_k; pr = pr_k; x = xk; y = yk; r = w - S_N - E_N; }
    else return;
    float a[8];
    spmm_row_compute(rp, pr, x, r, l, a);
    spmm_store(y, r, l, a);
}

// vectorized gather-accumulate (float4 per lane)
__device__ __forceinline__ void gather_accb_body4(
        int i4, const int* __restrict__ sid, const int* __restrict__ eid,
        const ushort* __restrict__ src_s, const ushort* __restrict__ src_e,
        const ushort* __restrict__ src_k,
        float* bacc_s, float* bacc_e, float* kacc) {
    if (i4 >= GTOT4) return;
    int base = i4 * 4;
    const int BD = B_N * 64;
    const ushort* src; float* acc; long soff; int aoff;
    if (base < BD) {
        int b = base >> 6, d0 = base & 63;
        src = src_s; acc = bacc_s; soff = (long)sid[b] * 64 + d0; aoff = base;
    } else if (base < 2 * BD) {
        int bb = base - BD; int b = bb >> 6, d0 = bb & 63;
        src = src_e; acc = bacc_e; soff = (long)eid[b] * 64 + d0; aoff = bb;
    } else {
        int bb = base - 2 * BD;
        src = src_k; acc = kacc; soff = bb; aoff = bb;
    }
    ushort4 v = *(const ushort4*)&src[soff];
    float4 a = *(const float4*)&acc[aoff];
    a.x += b2f(v.x); a.y += b2f(v.y); a.z += b2f(v.z); a.w += b2f(v.w);
    *(float4*)&acc[aoff] = a;
}

// layer-1: full-table spmm only
__global__ void spmm_l1(const int* __restrict__ rp_s, const int2* __restrict__ pr_s,
                        const ushort* __restrict__ xs, ushort* ys,
                        const int* __restrict__ rp_e, const int2* __restrict__ pr_e,
                        const ushort* __restrict__ xe, ushort* ye,
                        const int* __restrict__ rp_k, const int2* __restrict__ pr_k,
                        const ushort* __restrict__ xk, ushort* yk) {
    spmm_full_body(blockIdx.x, threadIdx.x, rp_s, pr_s, xs, ys,
                   rp_e, pr_e, xe, ye, rp_k, pr_k, xk, yk);
}

// layer-2: full-table spmm (bufA->bufB) fused with gather_accb(bufA)
__global__ void spmm_l2_fused(const int* __restrict__ rp_s, const int2* __restrict__ pr_s,
                              const ushort* __restrict__ xs, ushort* ys,
                              const int* __restrict__ rp_e, const int2* __restrict__ pr_e,
                              const ushort* __restrict__ xe, ushort* ye,
                              const int* __restrict__ rp_k, const int2* __restrict__ pr_k,
                              const ushort* __restrict__ xk, ushort* yk,
                              const int* __restrict__ sid, const int* __restrict__ eid,
                              float* bacc_s, float* bacc_e, float* kacc) {
    int blk = blockIdx.x;
    if (blk < FULLB) {
        spmm_full_body(blk, threadIdx.x, rp_s, pr_s, xs, ys,
                       rp_e, pr_e, xe, ye, rp_k, pr_k, xk, yk);
    } else {
        int i4 = (blk - FULLB) * 256 + threadIdx.x;
        gather_accb_body4(i4, sid, eid, xs, xe, xk, bacc_s, bacc_e, kacc);
    }
}

// layer-3: batch-rows spmm (bufB->c3) + full K, fused with gather_accb(bufB)
__global__ void spmm_l3_fused(const int* __restrict__ sid, const int* __restrict__ eid,
                              const int* __restrict__ rp_s, const int2* __restrict__ pr_s,
                              const ushort* __restrict__ xs, ushort* c3s,
                              const int* __restrict__ rp_e, const int2* __restrict__ pr_e,
                              const ushort* __restrict__ xe, ushort* c3e,
                              const int* __restrict__ rp_k, const int2* __restrict__ pr_k,
                              const ushort* __restrict__ xk, ushort* yk,
                              float* bacc_s, float* bacc_e, float* kacc) {
    int blk = blockIdx.x;
    int t = threadIdx.x;
    if (blk < LASTB) {
        int w = (blk * 256 + t) >> 3;
        int l = t & 7;
        const int* rp; const int2* pr; const ushort* x; ushort* y; int r; int orow;
        if (w < B_N) { rp = rp_s; pr = pr_s; x = xs; y = c3s; r = sid[w]; orow = w; }
        else if (w < 2 * B_N) {
            int b = w - B_N;
            rp = rp_e; pr = pr_e; x = xe; y = c3e; r = eid[b]; orow = b;
        } else if (w < 2 * B_N + K_N) {
            r = w - 2 * B_N;
            rp = rp_k; pr = pr_k; x = xk; y = yk; orow = r;
        } else return;
        float a[8];
        spmm_row_compute(rp, pr, x, r, l, a);
        spmm_store(y, orow, l, a);
    } else {
        int i4 = (blk - LASTB) * 256 + t;
        gather_accb_body4(i4, sid, eid, xs, xe, xk, bacc_s, bacc_e, kacc);
    }
}

// =============================================================== post kernel
// fuses dense_mm | know_mm | disc. Dense blocks cover 8 rows each with a
// register-shared W value across 4 row-accumulators (W L2 traffic /4).
__global__ void post_kernel(const float* __restrict__ bacc_s, const ushort* __restrict__ c3_s,
                            const float* __restrict__ bacc_e, const ushort* __restrict__ c3_e,
                            const float* __restrict__ W_stu, const float* __restrict__ b_stu,
                            const float* __restrict__ W_exer, const float* __restrict__ b_exer,
                            __hip_bfloat16* st_b, __hip_bfloat16* df_b,
                            const float* __restrict__ kacc, const ushort* __restrict__ cur3_k,
                            const float* __restrict__ W_know, const float* __restrict__ b_know,
                            float* out_kn_f32, __hip_bfloat16* kn_b,
                            const float* __restrict__ W_disc, const float* __restrict__ b_disc,
                            float* out_disc) {
    int blk = blockIdx.x;
    int t = threadIdx.x;
    if (blk < NDENSE) {
        int which = blk >> 11;                 // 2048 blocks each
        int local = blk & 2047;
        const float* bacc = which ? bacc_e : bacc_s;
        const ushort* c3 = which ? c3_e : c3_s;
        const float* W = which ? W_exer : W_stu;
        const float* bias = which ? b_exer : b_stu;
        __hip_bfloat16* out = which ? df_b : st_b;
        int r0 = local * 8;
        __shared__ float X[8][64];
        // stage 8 rows (512 elems, 2 per thread)
        for (int i = t; i < 512; i += 256) {
            int lr = i >> 6, d = i & 63; int b = r0 + lr;
            X[lr][d] = 0.25f * (bacc[(long)b * 64 + d] + b2f(c3[(long)b * 64 + d]));
        }
        __syncthreads();
        int lr = t >> 7, f = t & 127;   // thread covers rows lr, lr+2, lr+4, lr+6
        float acc[4];
        #pragma unroll
        for (int rr = 0; rr < 4; rr++) acc[rr] = bias[f];
        for (int d = 0; d < 64; d++) {
            float wv = W[d * 128 + f];
            #pragma unroll
            for (int rr = 0; rr < 4; rr++) acc[rr] += X[rr * 2 + lr][d] * wv;
        }
        #pragma unroll
        for (int rr = 0; rr < 4; rr++) {
            float a = acc[rr];
            a = a > 0.f ? a : 0.1f * a;
            out[(long)(r0 + rr * 2 + lr) * 128 + f] = __float2bfloat16(a);
        }
    } else if (blk < NDENSE + NKNOW) {
        int r0 = (blk - NDENSE) * 8;
        __shared__ float X[8][64];
        for (int i = t; i < 512; i += 256) {
            int lr = i >> 6, d = i & 63; int r = r0 + lr;
            X[lr][d] = (r < K_N) ? 0.25f * (kacc[r * 64 + d] + b2f(cur3_k[r * 64 + d])) : 0.f;
        }
        __syncthreads();
        int lr = t >> 7, f = t & 127;
        float acc[4];
        #pragma unroll
        for (int rr = 0; rr < 4; rr++) acc[rr] = b_know[f];
        for (int d = 0; d < 64; d++) {
            float wv = W_know[d * 128 + f];
            #pragma unroll
            for (int rr = 0; rr < 4; rr++) acc[rr] += X[rr * 2 + lr][d] * wv;
        }
        #pragma unroll
        for (int rr = 0; rr < 4; rr++) {
            int r = r0 + rr * 2 + lr;
            float a = acc[rr];
            a = a > 0.f ? a : 0.1f * a;
            if (r < K_N) {
                out_kn_f32[(long)r * 128 + f] = a;
                kn_b[(long)r * 128 + f] = __float2bfloat16(a);
            } else {
                kn_b[(long)r * 128 + f] = __float2bfloat16(0.f);
            }
        }
    } else {
        int w = ((blk - NDENSE - NKNOW) * 256 + t) >> 6;
        int d = t & 63;
        if (w >= B_N) return;
        float x = 0.25f * (bacc_e[(long)w * 64 + d] + b2f(c3_e[(long)w * 64 + d])) * W_disc[d];
        for (int off = 32; off > 0; off >>= 1) x += __shfl_down(x, off, 64);
        if (d == 0) {
            float z = x + b_disc[0];
            out_disc[w] = 1.f / (1.f + expf(-z));
        }
    }
}

// --------------------------------------------- big GEMM: [B,128] @ [128,1024p]^T
// block = 64 rows x 256 cols (wave: 32x128 = 2x8 mfma tiles)
__global__ void big_mm(const __hip_bfloat16* __restrict__ st, const __hip_bfloat16* __restrict__ df,
                       const __hip_bfloat16* __restrict__ kn,
                       float* __restrict__ out0, float* __restrict__ out1) {
    const ushort* X = (const ushort*)(blockIdx.z ? df : st);
    const ushort* Kn = (const ushort*)kn;
    float* out = blockIdx.z ? out1 : out0;
    int wv = threadIdx.x >> 6;
    int lane = threadIdx.x & 63;
    int m_blk = blockIdx.y * 64 + (wv >> 1) * 32;
    int n_blk = blockIdx.x * 256 + (wv & 1) * 128;
    int q = lane >> 4, l16 = lane & 15;
    f4 acc0[8], acc1[8];
    #pragma unroll
    for (int nt = 0; nt < 8; nt++) { acc0[nt] = {0.f, 0.f, 0.f, 0.f}; acc1[nt] = acc0[nt]; }
    for (int s = 0; s < 4; s++) {
        int kofs = s * 32 + q * 8;
        sh8 a0 = *(const sh8*)&X[(long)(m_blk + l16) * 128 + kofs];
        sh8 a1 = *(const sh8*)&X[(long)(m_blk + 16 + l16) * 128 + kofs];
        #pragma unroll
        for (int nt = 0; nt < 8; nt++) {
            sh8 bb = *(const sh8*)&Kn[(long)(n_blk + nt * 16 + l16) * 128 + kofs];
            acc0[nt] = __builtin_amdgcn_mfma_f32_16x16x32_bf16(a0, bb, acc0[nt], 0, 0, 0);
            acc1[nt] = __builtin_amdgcn_mfma_f32_16x16x32_bf16(a1, bb, acc1[nt], 0, 0, 0);
        }
    }
    // C/D layout: col = lane&15, row = (lane>>4)*4 + reg
    #pragma unroll
    for (int nt = 0; nt < 8; nt++) {
        int col = n_blk + nt * 16 + l16;
        if (col >= K_N) continue;
        #pragma unroll
        for (int r = 0; r < 4; r++) {
            out[(long)(m_blk + q * 4 + r) * K_N + col] = acc0[nt][r];
            out[(long)(m_blk + 16 + q * 4 + r) * K_N + col] = acc1[nt][r];
        }
    }
}

// ---------------------------------------------------------------------------
extern "C" void kernel_launch(void* const* d_in, const int* in_sizes, int n_in,
                              void* d_out, int out_size, void* d_ws, size_t ws_size,
                              hipStream_t stream) {
    const int* sid = (const int*)d_in[0];
    const int* eid = (const int*)d_in[1];
    // d_in[2] q_mask unused
    const float* stu_emb = (const float*)d_in[3];
    const float* exer_emb = (const float*)d_in[4];
    const float* know_emb = (const float*)d_in[5];
    const float* impact_emb = (const float*)d_in[6];
    const int* s_rows = (const int*)d_in[7];
    const int* s_cols = (const int*)d_in[8];
    const float* s_vals = (const float*)d_in[9];
    const int* e_rows = (const int*)d_in[10];
    const int* e_cols = (const int*)d_in[11];
    const float* e_vals = (const float*)d_in[12];
    const int* k_rows = (const int*)d_in[13];
    const int* k_cols = (const int*)d_in[14];
    const float* k_vals = (const float*)d_in[15];
    const float* W_stu = (const float*)d_in[16];
    const float* b_stu = (const float*)d_in[17];
    const float* W_exer = (const float*)d_in[18];
    const float* b_exer = (const float*)d_in[19];
    const float* W_know = (const float*)d_in[20];
    const float* b_know = (const float*)d_in[21];
    const float* W_disc = (const float*)d_in[22];
    const float* b_disc = (const float*)d_in[23];

    float* out = (float*)d_out;
    float* out_st = out;                       // [B,1000]
    float* out_df = out + 16384000;            // [B,1000]
    float* out_disc = out + 32768000;          // [B,1]
    float* out_kn = out + 32784384;            // [1000,128]
    float* out_imp = out + 32912384;           // [B,64]

    char* p = (char*)d_ws;
    auto alloc = [&](size_t bytes) -> char* {
        char* r = p;
        p += (bytes + 255) & ~(size_t)255;
        return r;
    };
    ushort* xb_s = (ushort*)alloc((size_t)S_N * 64 * 2);   // bf16 embeddings
    ushort* xb_e = (ushort*)alloc((size_t)E_N * 64 * 2);
    ushort* xb_k = (ushort*)alloc((size_t)K_N * 64 * 2);
    ushort* bufA_s = (ushort*)alloc((size_t)S_N * 64 * 2);
    ushort* bufB_s = (ushort*)alloc((size_t)S_N * 64 * 2);
    ushort* bufA_e = (ushort*)alloc((size_t)E_N * 64 * 2);
    ushort* bufB_e = (ushort*)alloc((size_t)E_N * 64 * 2);
    ushort* bufA_k = (ushort*)alloc((size_t)K_N * 64 * 2);
    ushort* bufB_k = (ushort*)alloc((size_t)K_N * 64 * 2);
    ushort* c3s = (ushort*)alloc((size_t)B_N * 64 * 2);    // layer-3 per-batch rows
    ushort* c3e = (ushort*)alloc((size_t)B_N * 64 * 2);
    float* bacc_s = (float*)alloc((size_t)B_N * 64 * 4);
    float* bacc_e = (float*)alloc((size_t)B_N * 64 * 4);
    float* kacc = (float*)alloc((size_t)K_N * 64 * 4);
    __hip_bfloat16* st_b = (__hip_bfloat16*)alloc((size_t)B_N * 128 * 2);
    __hip_bfloat16* df_b = (__hip_bfloat16*)alloc((size_t)B_N * 128 * 2);
    __hip_bfloat16* kn_b = (__hip_bfloat16*)alloc((size_t)1024 * 128 * 2);
    // bucket totals + reservation cursors (zeroed together)
    int* bcnt_tot = (int*)alloc((size_t)2 * NB_TOT * 4);
    int* rsv = bcnt_tot + NB_TOT;
    int* rp_s = (int*)alloc((size_t)(S_N + 1) * 4);
    int* rp_e = (int*)alloc((size_t)(E_N + 1) * 4);
    int* rp_k = (int*)alloc((size_t)(K_N + 1) * 4);
    int2* stg_s = (int2*)alloc((size_t)NNZ_S * 8);
    int2* stg_e = (int2*)alloc((size_t)NNZ_E * 8);
    int2* stg_k = (int2*)alloc((size_t)NNZ_K * 8);
    int2* pr_s = (int2*)alloc((size_t)NNZ_S * 8);
    int2* pr_e = (int2*)alloc((size_t)NNZ_E * 8);
    int2* pr_k = (int2*)alloc((size_t)NNZ_K * 8);

    // 1) zero counters
    hipMemsetAsync(bcnt_tot, 0, (size_t)2 * NB_TOT * 4, stream);
    // 2) fused: convert + gather_init + bucket_count + impact
    pre_kernel<<<NCONV + NGATH4 + SB_TOT + NIMP4, 256, 0, stream>>>(
        stu_emb, exer_emb, know_emb, xb_s, xb_e, xb_k,
        sid, eid, bacc_s, bacc_e, kacc,
        s_rows, e_rows, k_rows, bcnt_tot, impact_emb, out_imp);
    // 3) stage1 (inline segment scan)
    stage1_bin<<<SB_TOT, 256, 0, stream>>>(
        s_rows, s_cols, s_vals, e_rows, e_cols, e_vals, k_rows, k_cols, k_vals,
        bcnt_tot, rsv, stg_s, stg_e, stg_k);
    // 4) stage2 (inline prefix, writes rp directly)
    stage2_place<<<NB_TOT, 256, 0, stream>>>(bcnt_tot,
                                             stg_s, pr_s, rp_s,
                                             stg_e, pr_e, rp_e,
                                             stg_k, pr_k, rp_k);
    // 5) layer-1 spmm
    spmm_l1<<<FULLB, 256, 0, stream>>>(rp_s, pr_s, xb_s, bufA_s,
                                       rp_e, pr_e, xb_e, bufA_e,
                                       rp_k, pr_k, xb_k, bufA_k);
    // 6) layer-2 spmm + gather_accb(bufA)
    spmm_l2_fused<<<FULLB + NGATH4, 256, 0, stream>>>(
        rp_s, pr_s, bufA_s, bufB_s,
        rp_e, pr_e, bufA_e, bufB_e,
        rp_k, pr_k, bufA_k, bufB_k,
        sid, eid, bacc_s, bacc_e, kacc);
    // 7) layer-3 batched spmm + gather_accb(bufB)
    spmm_l3_fused<<<LASTB + NGATH4, 256, 0, stream>>>(
        sid, eid,
        rp_s, pr_s, bufB_s, c3s,
        rp_e, pr_e, bufB_e, c3e,
        rp_k, pr_k, bufB_k, bufA_k,
        bacc_s, bacc_e, kacc);
    // 8) fused dense stage (8-row dense blocks)
    post_kernel<<<NDENSE + NKNOW + NDISC, 256, 0, stream>>>(
        bacc_s, c3s, bacc_e, c3e, W_stu, b_stu, W_exer, b_exer, st_b, df_b,
        kacc, bufA_k, W_know, b_know, out_kn, kn_b,
        W_disc, b_disc, out_disc);
    // 9) big GEMMs (64x256 blocks)
    big_mm<<<dim3(4, B_N / 64, 2), 256, 0, stream>>>(st_b, df_b, kn_b, out_st, out_df);
}